// Round 15
// baseline (129.770 us; speedup 1.0000x reference)
//
#include <hip/hip_runtime.h>

#define CEILDIV(a,b) (((a)+(b)-1)/(b))

constexpr int BKCAP  = 1536;  // edges per 64-node bucket (mean 819, ~25 sigma)
constexpr int MAXBK  = 1024;  // max buckets (N <= 65536)
constexpr int CHUNKA = 4096;  // edges per pass-A block

// -------------------------------------------------------------- bf16 helpers

__device__ __forceinline__ unsigned short f2bf(float f) {
  union { float f; unsigned u; } v; v.f = f;
  unsigned u = v.u + (0x7fffu + ((v.u >> 16) & 1u));  // RNE
  return (unsigned short)(u >> 16);
}
__device__ __forceinline__ unsigned pack2(float lo, float hi) {
  return (unsigned)f2bf(lo) | ((unsigned)f2bf(hi) << 16);
}
__device__ __forceinline__ void add2(float* a, unsigned w) {
  union { unsigned u; float f; } lo, hi;
  lo.u = w << 16; hi.u = w & 0xffff0000u;
  a[0] += lo.f; a[1] += hi.f;
}
__device__ __forceinline__ void add8(float* a, uint4 w) {
  add2(a + 0, w.x); add2(a + 2, w.y); add2(a + 4, w.z); add2(a + 6, w.w);
}
__device__ __forceinline__ void fma2(float* a, unsigned w, float s) {
  union { unsigned u; float f; } lo, hi;
  lo.u = w << 16; hi.u = w & 0xffff0000u;
  a[0] = fmaf(lo.f, s, a[0]); a[1] = fmaf(hi.f, s, a[1]);
}
__device__ __forceinline__ void fma8(float* a, uint4 w, float s) {
  fma2(a + 0, w.x, s); fma2(a + 2, w.y, s); fma2(a + 4, w.z, s); fma2(a + 6, w.w, s);
}

// ---------------------------------------------------------------- edge prep

// ctrl[0]=int64 flag; ctrl[8+b]=bucket cursor. Single block.
__global__ __launch_bounds__(256) void k_init(const int* __restrict__ raw,
                                              int* __restrict__ ctrl, int E) {
  const int tid = threadIdx.x;
  for (int i = 1 + tid; i < 8 + MAXBK; i += 256) ctrl[i] = 0;
  __shared__ int ok;
  if (tid == 0) ok = 1;
  __syncthreads();
  int n = (E < 1024) ? E : 1024;
  for (int i = tid; i < n; i += 256)
    if (raw[2 * i + 1] != 0) ok = 0;
  __syncthreads();
  if (tid == 0) ctrl[0] = ok;
}

// ---------------------------------------------------------------- GEMM body
// Y[r][c] = bf16( (X[r][:] @ W[:][c]) * (SCALE ? rsqrt(cnt[r]+1) : 1) )
// X fp32 or bf16. 128-row tiles, KC=32 (fewer barriers), smem passed in so
// callers can union it with other LDS uses. 256 threads.
template <int K, int NO, bool XBF16, bool SCALE>
__device__ __forceinline__ void gemm_body(char* smem_raw,
                                          const void* __restrict__ Xv,
                                          const float* __restrict__ W,
                                          const int* __restrict__ cnt,
                                          unsigned short* __restrict__ Y,
                                          int N, int bid) {
  constexpr int ROWS = 128, KC = 32, TC = NO / 16;
  constexpr int XST = ROWS + 4;
  constexpr int WST = NO + 4;
  float* xs = (float*)smem_raw;       // [KC][XST] transposed
  float* ws = xs + KC * XST;          // [KC][WST]
  const int tid = threadIdx.x;
  const int tx = tid & 15, ty = tid >> 4;
  const int r0 = ty * 8;
  const int row0 = bid * ROWS;

  float acc[8][TC];
#pragma unroll
  for (int i = 0; i < 8; ++i)
#pragma unroll
    for (int j = 0; j < TC; ++j) acc[i][j] = 0.0f;

  for (int kk = 0; kk < K; kk += KC) {
#pragma unroll
    for (int it = 0; it < (ROWS * KC / 4) / 256; ++it) {
      int idx = it * 256 + tid;
      int r = idx / (KC / 4), kq = idx % (KC / 4);
      int row = row0 + r; if (row >= N) row = N - 1;
      float f0, f1, f2, f3;
      if constexpr (XBF16) {
        const unsigned short* Xb = (const unsigned short*)Xv;
        uint2 v = *(const uint2*)&Xb[(size_t)row * K + kk + kq * 4];
        union { unsigned u; float f; } t0, t1, t2, t3;
        t0.u = v.x << 16; t1.u = v.x & 0xffff0000u;
        t2.u = v.y << 16; t3.u = v.y & 0xffff0000u;
        f0 = t0.f; f1 = t1.f; f2 = t2.f; f3 = t3.f;
      } else {
        const float* Xf = (const float*)Xv;
        float4 v = *(const float4*)&Xf[(size_t)row * K + kk + kq * 4];
        f0 = v.x; f1 = v.y; f2 = v.z; f3 = v.w;
      }
      xs[(kq * 4 + 0) * XST + r] = f0;
      xs[(kq * 4 + 1) * XST + r] = f1;
      xs[(kq * 4 + 2) * XST + r] = f2;
      xs[(kq * 4 + 3) * XST + r] = f3;
    }
#pragma unroll
    for (int it = 0; it < (KC * NO / 4) / 256; ++it) {
      int idx = it * 256 + tid;
      int c4 = idx & (NO / 4 - 1), kw = idx / (NO / 4);
      float4 v = *(const float4*)&W[(size_t)(kk + kw) * NO + c4 * 4];
      *(float4*)&ws[kw * WST + c4 * 4] = v;
    }
    __syncthreads();
#pragma unroll 8
    for (int k = 0; k < KC; ++k) {
      const float4 xa = *(const float4*)&xs[k * XST + r0];
      const float4 xb = *(const float4*)&xs[k * XST + r0 + 4];
      float4 wv[TC / 4];
      wv[0] = *(const float4*)&ws[k * WST + tx * 4];
      if constexpr (TC == 8)
        wv[1] = *(const float4*)&ws[k * WST + 64 + tx * 4];
      const float xr[8] = {xa.x, xa.y, xa.z, xa.w, xb.x, xb.y, xb.z, xb.w};
#pragma unroll
      for (int i = 0; i < 8; ++i)
#pragma unroll
        for (int j4 = 0; j4 < TC / 4; ++j4) {
          acc[i][j4 * 4 + 0] += xr[i] * wv[j4].x;
          acc[i][j4 * 4 + 1] += xr[i] * wv[j4].y;
          acc[i][j4 * 4 + 2] += xr[i] * wv[j4].z;
          acc[i][j4 * 4 + 3] += xr[i] * wv[j4].w;
        }
    }
    __syncthreads();
  }
#pragma unroll
  for (int i = 0; i < 8; ++i) {
    int r = row0 + r0 + i;
    if (r < N) {
      const float dv = SCALE ? rsqrtf((float)(cnt[r] + 1)) : 1.0f;
      uint2 pa = make_uint2(pack2(acc[i][0] * dv, acc[i][1] * dv),
                            pack2(acc[i][2] * dv, acc[i][3] * dv));
      *(uint2*)&Y[(size_t)r * NO + tx * 4] = pa;
      if constexpr (TC == 8) {
        uint2 pb = make_uint2(pack2(acc[i][4] * dv, acc[i][5] * dv),
                              pack2(acc[i][6] * dv, acc[i][7] * dv));
        *(uint2*)&Y[(size_t)r * NO + 64 + tx * 4] = pb;
      }
    }
  }
}

constexpr int GEMM1_SMEM = (32 * 132 + 32 * 132) * 4;  // 33792 B
constexpr int GEMM2_SMEM = (32 * 132 + 32 * 68) * 4;   // 25600 B

// ------------------------------ L1: pass-A bucket  ||  gemm1 (bids [0,G1))
__global__ __launch_bounds__(256, 4) void k_work1(
    const float* __restrict__ X, const float* __restrict__ W1,
    unsigned short* __restrict__ hb1, int N, int FA,
    const int* __restrict__ raw, int* __restrict__ ctrl,
    unsigned* __restrict__ ebuf, int E, int nbk) {
  __shared__ __align__(16) char smem[GEMM1_SMEM];  // unioned: gemm | fill
  const int i = blockIdx.x;
  if (i >= FA) {  // gemm1 (unscaled; dinv applied in agg1)
    gemm_body<128, 128, false, false>(smem, X, W1, nullptr, hb1, N, i - FA);
    return;
  }
  int* lcnt  = (int*)smem;         // [MAXBK]
  int* lbase = lcnt + MAXBK;
  int* lrank = lbase + MAXBK;
  const int tid = threadIdx.x;
  for (int b = tid; b < nbk; b += 256) { lcnt[b] = 0; lrank[b] = 0; }
  __syncthreads();
  const bool is64 = (ctrl[0] != 0);
  const int e0 = i * CHUNKA;
  const int e1 = min(E, e0 + CHUNKA);
  if ((E & 3) == 0) {
    // count pass (vectorized dst reads)
    for (int e = e0 + tid * 4; e < e1; e += 1024) {
      int d0, d1, d2, d3;
      if (is64) {
        uint4 a = *(const uint4*)&raw[2 * (E + e)];
        uint4 b = *(const uint4*)&raw[2 * (E + e) + 4];
        d0 = (int)a.x; d1 = (int)a.z; d2 = (int)b.x; d3 = (int)b.z;
      } else {
        uint4 v = *(const uint4*)&raw[E + e];
        d0 = (int)v.x; d1 = (int)v.y; d2 = (int)v.z; d3 = (int)v.w;
      }
      atomicAdd(&lcnt[d0 >> 6], 1); atomicAdd(&lcnt[d1 >> 6], 1);
      atomicAdd(&lcnt[d2 >> 6], 1); atomicAdd(&lcnt[d3 >> 6], 1);
    }
    __syncthreads();
    for (int b = tid; b < nbk; b += 256)
      if (lcnt[b]) lbase[b] = atomicAdd(&ctrl[8 + b], lcnt[b]);
    __syncthreads();
    // write pass (vectorized src+dst reads)
    for (int e = e0 + tid * 4; e < e1; e += 1024) {
      int s[4], d[4];
      if (is64) {
        uint4 sa = *(const uint4*)&raw[2 * e];
        uint4 sb = *(const uint4*)&raw[2 * e + 4];
        uint4 da = *(const uint4*)&raw[2 * (E + e)];
        uint4 db = *(const uint4*)&raw[2 * (E + e) + 4];
        s[0] = (int)sa.x; s[1] = (int)sa.z; s[2] = (int)sb.x; s[3] = (int)sb.z;
        d[0] = (int)da.x; d[1] = (int)da.z; d[2] = (int)db.x; d[3] = (int)db.z;
      } else {
        uint4 sv = *(const uint4*)&raw[e];
        uint4 dv = *(const uint4*)&raw[E + e];
        s[0] = (int)sv.x; s[1] = (int)sv.y; s[2] = (int)sv.z; s[3] = (int)sv.w;
        d[0] = (int)dv.x; d[1] = (int)dv.y; d[2] = (int)dv.z; d[3] = (int)dv.w;
      }
#pragma unroll
      for (int j = 0; j < 4; ++j) {
        int bk = d[j] >> 6;
        int r = atomicAdd(&lrank[bk], 1);
        int pos = lbase[bk] + r;
        if (pos < BKCAP)
          ebuf[(size_t)bk * BKCAP + pos] =
              (unsigned)s[j] | ((unsigned)(d[j] & 63) << 17);
      }
    }
  } else {  // generic scalar fallback
    for (int e = e0 + tid; e < e1; e += 256) {
      int d = is64 ? raw[2 * (E + e)] : raw[E + e];
      atomicAdd(&lcnt[d >> 6], 1);
    }
    __syncthreads();
    for (int b = tid; b < nbk; b += 256)
      if (lcnt[b]) lbase[b] = atomicAdd(&ctrl[8 + b], lcnt[b]);
    __syncthreads();
    for (int e = e0 + tid; e < e1; e += 256) {
      int s = is64 ? raw[2 * e] : raw[e];
      int d = is64 ? raw[2 * (E + e)] : raw[E + e];
      int bk = d >> 6;
      int r = atomicAdd(&lrank[bk], 1);
      int pos = lbase[bk] + r;
      if (pos < BKCAP)
        ebuf[(size_t)bk * BKCAP + pos] = (unsigned)s | ((unsigned)(d & 63) << 17);
    }
  }
}

// ------------------ L2: pass-B local CSR build  ||  gemm1 (bids [G1,GB))
__global__ __launch_bounds__(256, 4) void k_work2(
    const float* __restrict__ X, const float* __restrict__ W1,
    unsigned short* __restrict__ hb1, int N, int NBK, int G1,
    const unsigned* __restrict__ ebuf, const int* __restrict__ ctrl,
    int* __restrict__ cnt, int* __restrict__ rowptr,
    int* __restrict__ esrc) {
  __shared__ __align__(16) char smem[GEMM1_SMEM];  // unioned: gemm | csr
  const int i = blockIdx.x;
  if (i >= NBK) {  // gemm1 remainder
    gemm_body<128, 128, false, false>(smem, X, W1, nullptr, hb1, N,
                                      G1 + (i - NBK));
    return;
  }
  int* lcnt  = (int*)smem;   // [64]
  int* lbase = lcnt + 64;
  int* lrank = lbase + 64;
  const int tid = threadIdx.x;
  if (tid < 64) { lcnt[tid] = 0; lrank[tid] = 0; }
  __syncthreads();
  const int nb = min(ctrl[8 + i], BKCAP);
  const unsigned* __restrict__ eb = &ebuf[(size_t)i * BKCAP];
  for (int j = tid; j < nb; j += 256) atomicAdd(&lcnt[eb[j] >> 17], 1);
  __syncthreads();
  if (tid == 0) {
    int run = 0;
#pragma unroll
    for (int j = 0; j < 64; ++j) { lbase[j] = run; run += lcnt[j]; }
  }
  __syncthreads();
  if (tid < 64) {
    int v = i * 64 + tid;
    if (v < N) {
      cnt[v] = lcnt[tid];
      rowptr[v] = i * BKCAP + lbase[tid];
    }
  }
  for (int j = tid; j < nb; j += 256) {
    unsigned u = eb[j];
    int ld = (int)(u >> 17);
    int r = atomicAdd(&lrank[ld], 1);
    esrc[(size_t)i * BKCAP + lbase[ld] + r] = (int)(u & 0x1FFFFu);
  }
}

// -------------------------------------------- layer-1 aggregation (weighted)
// h1 unscaled bf16:
//   ab1[v] = bf16(relu( dv_v*(sum_e h1[s]*dv_s + h1[v]*dv_v) + b1 ))
__global__ __launch_bounds__(256) void k_agg1(const unsigned short* __restrict__ h,
                                              const int* __restrict__ cnt,
                                              const int* __restrict__ rowptr,
                                              const int* __restrict__ esrc,
                                              const float* __restrict__ bias,
                                              unsigned short* __restrict__ out,
                                              int N) {
  const int v = blockIdx.x * 16 + (threadIdx.x >> 4);
  if (v >= N) return;
  const int lc = threadIdx.x & 15;
  const uint4* __restrict__ h4 = (const uint4*)h;

  const int deg = cnt[v];
  const float dv = rsqrtf((float)(deg + 1));
  float acc[8] = {0, 0, 0, 0, 0, 0, 0, 0};
  fma8(acc, h4[(size_t)v * 16 + lc], dv);  // self-loop (x dv again at end)
  const int* __restrict__ ep = &esrc[rowptr[v]];
  int e = 0;
  for (; e + 4 <= deg; e += 4) {
    int s0 = ep[e + 0], s1 = ep[e + 1], s2 = ep[e + 2], s3 = ep[e + 3];
    float w0 = rsqrtf((float)(cnt[s0] + 1));
    float w1 = rsqrtf((float)(cnt[s1] + 1));
    float w2 = rsqrtf((float)(cnt[s2] + 1));
    float w3 = rsqrtf((float)(cnt[s3] + 1));
    uint4 a0 = h4[(size_t)s0 * 16 + lc];
    uint4 a1 = h4[(size_t)s1 * 16 + lc];
    uint4 a2 = h4[(size_t)s2 * 16 + lc];
    uint4 a3 = h4[(size_t)s3 * 16 + lc];
    fma8(acc, a0, w0); fma8(acc, a1, w1); fma8(acc, a2, w2); fma8(acc, a3, w3);
  }
  for (; e < deg; ++e) {
    int s = ep[e];
    fma8(acc, h4[(size_t)s * 16 + lc], rsqrtf((float)(cnt[s] + 1)));
  }

  const float4 b0 = *(const float4*)&bias[lc * 8];
  const float4 b1 = *(const float4*)&bias[lc * 8 + 4];
  float r[8];
  r[0] = fmaxf(acc[0] * dv + b0.x, 0.0f);
  r[1] = fmaxf(acc[1] * dv + b0.y, 0.0f);
  r[2] = fmaxf(acc[2] * dv + b0.z, 0.0f);
  r[3] = fmaxf(acc[3] * dv + b0.w, 0.0f);
  r[4] = fmaxf(acc[4] * dv + b1.x, 0.0f);
  r[5] = fmaxf(acc[5] * dv + b1.y, 0.0f);
  r[6] = fmaxf(acc[6] * dv + b1.z, 0.0f);
  r[7] = fmaxf(acc[7] * dv + b1.w, 0.0f);
  uint4 pk = make_uint4(pack2(r[0], r[1]), pack2(r[2], r[3]),
                        pack2(r[4], r[5]), pack2(r[6], r[7]));
  ((uint4*)out)[(size_t)v * 16 + lc] = pk;
}

// -------------------------------------------------------- layer-2 GEMM
__global__ __launch_bounds__(256, 4) void k_gemm2(const unsigned short* __restrict__ X,
                                                  const float* __restrict__ W,
                                                  const int* __restrict__ cnt,
                                                  unsigned short* __restrict__ Y,
                                                  int N) {
  __shared__ __align__(16) char smem[GEMM2_SMEM];
  gemm_body<128, 64, true, true>(smem, X, W, cnt, Y, N, blockIdx.x);
}

// ------------------------------------------- layer-2 aggregation (prescaled)
// out[v] = dv_v*(sum h2[s] + h2[v]) + b2   (fp32 out)
__global__ __launch_bounds__(256) void k_agg2(const unsigned short* __restrict__ h,
                                              const int* __restrict__ cnt,
                                              const int* __restrict__ rowptr,
                                              const int* __restrict__ esrc,
                                              const float* __restrict__ bias,
                                              float* __restrict__ out, int N) {
  constexpr int F = 64, LPN = 8, NPB = 32;
  const int v = blockIdx.x * NPB + threadIdx.x / LPN;
  if (v >= N) return;
  const int lc = threadIdx.x % LPN;
  const uint4* __restrict__ h4 = (const uint4*)h;

  float acc[8] = {0, 0, 0, 0, 0, 0, 0, 0};
  add8(acc, h4[(size_t)v * LPN + lc]);  // self-loop (dinv[v]-prescaled)
  const int deg = cnt[v];
  const float dv = rsqrtf((float)(deg + 1));
  const int* __restrict__ ep = &esrc[rowptr[v]];
  int e = 0;
  for (; e + 4 <= deg; e += 4) {
    int s0 = ep[e + 0], s1 = ep[e + 1], s2 = ep[e + 2], s3 = ep[e + 3];
    uint4 a0 = h4[(size_t)s0 * LPN + lc];
    uint4 a1 = h4[(size_t)s1 * LPN + lc];
    uint4 a2 = h4[(size_t)s2 * LPN + lc];
    uint4 a3 = h4[(size_t)s3 * LPN + lc];
    add8(acc, a0); add8(acc, a1); add8(acc, a2); add8(acc, a3);
  }
  for (; e < deg; ++e) add8(acc, h4[(size_t)ep[e] * LPN + lc]);

  const float4 b0 = *(const float4*)&bias[lc * 8];
  const float4 b1 = *(const float4*)&bias[lc * 8 + 4];
  float4 o0, o1;
  o0.x = acc[0] * dv + b0.x; o0.y = acc[1] * dv + b0.y;
  o0.z = acc[2] * dv + b0.z; o0.w = acc[3] * dv + b0.w;
  o1.x = acc[4] * dv + b1.x; o1.y = acc[5] * dv + b1.y;
  o1.z = acc[6] * dv + b1.z; o1.w = acc[7] * dv + b1.w;
  float4* op = (float4*)(out + (size_t)v * F + lc * 8);
  op[0] = o0; op[1] = o1;
}

// ---------------------------------------------------------------- launcher

extern "C" void kernel_launch(void* const* d_in, const int* in_sizes, int n_in,
                              void* d_out, int out_size, void* d_ws, size_t ws_size,
                              hipStream_t stream) {
  const float* x  = (const float*)d_in[0];
  const int*   ei = (const int*)d_in[1];
  const float* W1 = (const float*)d_in[2];
  const float* b1 = (const float*)d_in[3];
  const float* W2 = (const float*)d_in[4];
  const float* b2 = (const float*)d_in[5];
  const int H    = in_sizes[3];        // 128
  const int Fin  = in_sizes[2] / H;    // 128
  const int N    = in_sizes[0] / Fin;  // 50000 (<= 65536 for 17-bit packing)
  const int E    = in_sizes[1] / 2;    // 640000
  const int FO   = in_sizes[5];        // 64
  float* outp = (float*)d_out;

  const int NBK = CEILDIV(N, 64);      // 782 buckets
  const int FA  = CEILDIV(E, CHUNKA);  // 157 pass-A blocks
  const int GB  = CEILDIV(N, 128);     // 391 gemm1 blocks
  const int G1  = GB / 2;              // gemm1 split 50/50 across L1/L2

  char* p = (char*)d_ws;
  auto alloc = [&](size_t bytes) {
    void* q = (void*)p;
    p += (bytes + 255) & ~(size_t)255;
    return q;
  };
  int*      ctrl   = (int*)alloc((8 + MAXBK) * 4);
  int*      cnt    = (int*)alloc((size_t)N * 4);
  int*      rowptr = (int*)alloc((size_t)N * 4);
  unsigned* ebuf   = (unsigned*)alloc((size_t)NBK * BKCAP * 4);
  int*      esrc   = (int*)alloc((size_t)NBK * BKCAP * 4);
  unsigned short* hb1 = (unsigned short*)alloc((size_t)N * H * 2);   // bf16 h1 (unscaled)
  unsigned short* ab1 = (unsigned short*)alloc((size_t)N * H * 2);   // bf16 relu act
  unsigned short* hb2 = (unsigned short*)alloc((size_t)N * FO * 2);  // bf16 h2 (prescaled)

  k_init<<<1, 256, 0, stream>>>(ei, ctrl, E);
  // L1: bucket pass A  ||  gemm1 bids [0, G1)
  k_work1<<<FA + G1, 256, 0, stream>>>(x, W1, hb1, N, FA, ei, ctrl, ebuf, E, NBK);
  // L2: per-bucket local CSR (no global atomics, burst writes) || gemm1 rest
  k_work2<<<NBK + (GB - G1), 256, 0, stream>>>(x, W1, hb1, N, NBK, G1, ebuf,
                                               ctrl, cnt, rowptr, esrc);
  // ab1 = bf16(relu(dinv*(weighted agg h1) + b1))
  k_agg1<<<CEILDIV(N, 16), 256, 0, stream>>>(hb1, cnt, rowptr, esrc, b1, ab1, N);
  // hb2 = bf16((ab1 @ W2) * dinv)
  k_gemm2<<<CEILDIV(N, 128), 256, 0, stream>>>(ab1, W2, cnt, hb2, N);
  // out = dv*(agg h2 + self) + b2
  k_agg2<<<CEILDIV(N, 32), 256, 0, stream>>>(hb2, cnt, rowptr, esrc, b2, outp, N);
}

// Round 16
// 116.263 us; speedup vs baseline: 1.1162x; 1.1162x over previous
//
#include <hip/hip_runtime.h>

#define CEILDIV(a,b) (((a)+(b)-1)/(b))

constexpr int BKCAP  = 1536;  // edges per 64-node bucket (mean 819, ~25 sigma)
constexpr int MAXBK  = 1024;  // max buckets (N <= 65536)
constexpr int CHUNKA = 4096;  // edges per pass-A block

// -------------------------------------------------------------- bf16 helpers

__device__ __forceinline__ unsigned short f2bf(float f) {
  union { float f; unsigned u; } v; v.f = f;
  unsigned u = v.u + (0x7fffu + ((v.u >> 16) & 1u));  // RNE
  return (unsigned short)(u >> 16);
}
__device__ __forceinline__ unsigned pack2(float lo, float hi) {
  return (unsigned)f2bf(lo) | ((unsigned)f2bf(hi) << 16);
}
__device__ __forceinline__ void add2(float* a, unsigned w) {
  union { unsigned u; float f; } lo, hi;
  lo.u = w << 16; hi.u = w & 0xffff0000u;
  a[0] += lo.f; a[1] += hi.f;
}
__device__ __forceinline__ void add8(float* a, uint4 w) {
  add2(a + 0, w.x); add2(a + 2, w.y); add2(a + 4, w.z); add2(a + 6, w.w);
}
__device__ __forceinline__ void fma2(float* a, unsigned w, float s) {
  union { unsigned u; float f; } lo, hi;
  lo.u = w << 16; hi.u = w & 0xffff0000u;
  a[0] = fmaf(lo.f, s, a[0]); a[1] = fmaf(hi.f, s, a[1]);
}
__device__ __forceinline__ void fma8(float* a, uint4 w, float s) {
  fma2(a + 0, w.x, s); fma2(a + 2, w.y, s); fma2(a + 4, w.z, s); fma2(a + 6, w.w, s);
}

// ---------------------------------------------------------------- edge prep

// ctrl[0]=int64 flag; ctrl[8+b]=bucket cursor. Single block.
__global__ __launch_bounds__(256) void k_init(const int* __restrict__ raw,
                                              int* __restrict__ ctrl, int E) {
  const int tid = threadIdx.x;
  for (int i = 1 + tid; i < 8 + MAXBK; i += 256) ctrl[i] = 0;
  __shared__ int ok;
  if (tid == 0) ok = 1;
  __syncthreads();
  int n = (E < 1024) ? E : 1024;
  for (int i = tid; i < n; i += 256)
    if (raw[2 * i + 1] != 0) ok = 0;
  __syncthreads();
  if (tid == 0) ctrl[0] = ok;
}

// ---------------------------------------------------------------- GEMM body
// Y[r][c] = bf16( (X[r][:] @ W[:][c]) * (SCALE ? rsqrt(cnt[r]+1) : 1) )
// X fp32 or bf16. 128-row tiles, KC=16 (16.9KB LDS), 256 threads.
template <int K, int NO, bool XBF16, bool SCALE>
__device__ __forceinline__ void gemm_body(const void* __restrict__ Xv,
                                          const float* __restrict__ W,
                                          const int* __restrict__ cnt,
                                          unsigned short* __restrict__ Y,
                                          int N, int bid) {
  constexpr int ROWS = 128, KC = 16, TC = NO / 16;
  constexpr int XST = ROWS + 4;
  constexpr int WST = NO + 4;
  __shared__ float xs[KC * XST];  // [k][r] transposed
  __shared__ float ws[KC * WST];  // [k][c]
  const int tid = threadIdx.x;
  const int tx = tid & 15, ty = tid >> 4;
  const int r0 = ty * 8;
  const int row0 = bid * ROWS;

  float acc[8][TC];
#pragma unroll
  for (int i = 0; i < 8; ++i)
#pragma unroll
    for (int j = 0; j < TC; ++j) acc[i][j] = 0.0f;

  for (int kk = 0; kk < K; kk += KC) {
#pragma unroll
    for (int it = 0; it < (ROWS * KC / 4) / 256; ++it) {
      int idx = it * 256 + tid;
      int r = idx >> 2, kq = idx & 3;
      int row = row0 + r; if (row >= N) row = N - 1;
      float f0, f1, f2, f3;
      if constexpr (XBF16) {
        const unsigned short* Xb = (const unsigned short*)Xv;
        uint2 v = *(const uint2*)&Xb[(size_t)row * K + kk + kq * 4];
        union { unsigned u; float f; } t0, t1, t2, t3;
        t0.u = v.x << 16; t1.u = v.x & 0xffff0000u;
        t2.u = v.y << 16; t3.u = v.y & 0xffff0000u;
        f0 = t0.f; f1 = t1.f; f2 = t2.f; f3 = t3.f;
      } else {
        const float* Xf = (const float*)Xv;
        float4 v = *(const float4*)&Xf[(size_t)row * K + kk + kq * 4];
        f0 = v.x; f1 = v.y; f2 = v.z; f3 = v.w;
      }
      xs[(kq * 4 + 0) * XST + r] = f0;
      xs[(kq * 4 + 1) * XST + r] = f1;
      xs[(kq * 4 + 2) * XST + r] = f2;
      xs[(kq * 4 + 3) * XST + r] = f3;
    }
#pragma unroll
    for (int it = 0; it < (KC * NO / 4) / 256; ++it) {
      int idx = it * 256 + tid;
      int c4 = idx & (NO / 4 - 1), kw = idx / (NO / 4);
      float4 v = *(const float4*)&W[(size_t)(kk + kw) * NO + c4 * 4];
      *(float4*)&ws[kw * WST + c4 * 4] = v;
    }
    __syncthreads();
#pragma unroll
    for (int k = 0; k < KC; ++k) {
      const float4 xa = *(const float4*)&xs[k * XST + r0];
      const float4 xb = *(const float4*)&xs[k * XST + r0 + 4];
      float4 wv[TC / 4];
      wv[0] = *(const float4*)&ws[k * WST + tx * 4];
      if constexpr (TC == 8)
        wv[1] = *(const float4*)&ws[k * WST + 64 + tx * 4];
      const float xr[8] = {xa.x, xa.y, xa.z, xa.w, xb.x, xb.y, xb.z, xb.w};
#pragma unroll
      for (int i = 0; i < 8; ++i)
#pragma unroll
        for (int j4 = 0; j4 < TC / 4; ++j4) {
          acc[i][j4 * 4 + 0] += xr[i] * wv[j4].x;
          acc[i][j4 * 4 + 1] += xr[i] * wv[j4].y;
          acc[i][j4 * 4 + 2] += xr[i] * wv[j4].z;
          acc[i][j4 * 4 + 3] += xr[i] * wv[j4].w;
        }
    }
    __syncthreads();
  }
#pragma unroll
  for (int i = 0; i < 8; ++i) {
    int r = row0 + r0 + i;
    if (r < N) {
      const float dv = SCALE ? rsqrtf((float)(cnt[r] + 1)) : 1.0f;
      uint2 pa = make_uint2(pack2(acc[i][0] * dv, acc[i][1] * dv),
                            pack2(acc[i][2] * dv, acc[i][3] * dv));
      *(uint2*)&Y[(size_t)r * NO + tx * 4] = pa;
      if constexpr (TC == 8) {
        uint2 pb = make_uint2(pack2(acc[i][4] * dv, acc[i][5] * dv),
                              pack2(acc[i][6] * dv, acc[i][7] * dv));
        *(uint2*)&Y[(size_t)r * NO + 64 + tx * 4] = pb;
      }
    }
  }
}

// ------------------------------ L1: pass-A bucket  ||  gemm1 (bids [0,G1))
// Pass A uses vectorized uint4 edge reads (4 edges/thread) when E%4==0.
__global__ __launch_bounds__(256, 4) void k_work1(
    const float* __restrict__ X, const float* __restrict__ W1,
    unsigned short* __restrict__ hb1, int N, int FA,
    const int* __restrict__ raw, int* __restrict__ ctrl,
    unsigned* __restrict__ ebuf, int E, int nbk) {
  const int i = blockIdx.x;
  if (i >= FA) {  // gemm1 (unscaled; dinv applied in agg1)
    gemm_body<128, 128, false, false>(X, W1, nullptr, hb1, N, i - FA);
    return;
  }
  __shared__ int lcnt[MAXBK], lbase[MAXBK], lrank[MAXBK];
  const int tid = threadIdx.x;
  for (int b = tid; b < nbk; b += 256) { lcnt[b] = 0; lrank[b] = 0; }
  __syncthreads();
  const bool is64 = (ctrl[0] != 0);
  const int e0 = i * CHUNKA;
  const int e1 = min(E, e0 + CHUNKA);
  if ((E & 3) == 0) {
    // count pass (vectorized dst reads)
    for (int e = e0 + tid * 4; e < e1; e += 1024) {
      int d0, d1, d2, d3;
      if (is64) {
        uint4 a = *(const uint4*)&raw[2 * (E + e)];
        uint4 b = *(const uint4*)&raw[2 * (E + e) + 4];
        d0 = (int)a.x; d1 = (int)a.z; d2 = (int)b.x; d3 = (int)b.z;
      } else {
        uint4 v = *(const uint4*)&raw[E + e];
        d0 = (int)v.x; d1 = (int)v.y; d2 = (int)v.z; d3 = (int)v.w;
      }
      atomicAdd(&lcnt[d0 >> 6], 1); atomicAdd(&lcnt[d1 >> 6], 1);
      atomicAdd(&lcnt[d2 >> 6], 1); atomicAdd(&lcnt[d3 >> 6], 1);
    }
    __syncthreads();
    for (int b = tid; b < nbk; b += 256)
      if (lcnt[b]) lbase[b] = atomicAdd(&ctrl[8 + b], lcnt[b]);
    __syncthreads();
    // write pass (vectorized src+dst reads)
    for (int e = e0 + tid * 4; e < e1; e += 1024) {
      int s[4], d[4];
      if (is64) {
        uint4 sa = *(const uint4*)&raw[2 * e];
        uint4 sb = *(const uint4*)&raw[2 * e + 4];
        uint4 da = *(const uint4*)&raw[2 * (E + e)];
        uint4 db = *(const uint4*)&raw[2 * (E + e) + 4];
        s[0] = (int)sa.x; s[1] = (int)sa.z; s[2] = (int)sb.x; s[3] = (int)sb.z;
        d[0] = (int)da.x; d[1] = (int)da.z; d[2] = (int)db.x; d[3] = (int)db.z;
      } else {
        uint4 sv = *(const uint4*)&raw[e];
        uint4 dv = *(const uint4*)&raw[E + e];
        s[0] = (int)sv.x; s[1] = (int)sv.y; s[2] = (int)sv.z; s[3] = (int)sv.w;
        d[0] = (int)dv.x; d[1] = (int)dv.y; d[2] = (int)dv.z; d[3] = (int)dv.w;
      }
#pragma unroll
      for (int j = 0; j < 4; ++j) {
        int bk = d[j] >> 6;
        int r = atomicAdd(&lrank[bk], 1);
        int pos = lbase[bk] + r;
        if (pos < BKCAP)
          ebuf[(size_t)bk * BKCAP + pos] =
              (unsigned)s[j] | ((unsigned)(d[j] & 63) << 17);
      }
    }
  } else {  // scalar fallback
    for (int e = e0 + tid; e < e1; e += 256) {
      int d = is64 ? raw[2 * (E + e)] : raw[E + e];
      atomicAdd(&lcnt[d >> 6], 1);
    }
    __syncthreads();
    for (int b = tid; b < nbk; b += 256)
      if (lcnt[b]) lbase[b] = atomicAdd(&ctrl[8 + b], lcnt[b]);
    __syncthreads();
    for (int e = e0 + tid; e < e1; e += 256) {
      int s = is64 ? raw[2 * e] : raw[e];
      int d = is64 ? raw[2 * (E + e)] : raw[E + e];
      int bk = d >> 6;
      int r = atomicAdd(&lrank[bk], 1);
      int pos = lbase[bk] + r;
      if (pos < BKCAP)
        ebuf[(size_t)bk * BKCAP + pos] = (unsigned)s | ((unsigned)(d & 63) << 17);
    }
  }
}

// ------------------ L2: pass-B local CSR build  ||  gemm1 (bids [G1,GB))
__global__ __launch_bounds__(256, 4) void k_work2(
    const float* __restrict__ X, const float* __restrict__ W1,
    unsigned short* __restrict__ hb1, int N, int NBK, int G1,
    const unsigned* __restrict__ ebuf, const int* __restrict__ ctrl,
    int* __restrict__ cnt, int* __restrict__ rowptr,
    int* __restrict__ esrc) {
  const int i = blockIdx.x;
  if (i >= NBK) {  // gemm1 remainder
    gemm_body<128, 128, false, false>(X, W1, nullptr, hb1, N, G1 + (i - NBK));
    return;
  }
  __shared__ int lcnt[64], lbase[64], lrank[64];
  const int tid = threadIdx.x;
  if (tid < 64) { lcnt[tid] = 0; lrank[tid] = 0; }
  __syncthreads();
  const int nb = min(ctrl[8 + i], BKCAP);
  const unsigned* __restrict__ eb = &ebuf[(size_t)i * BKCAP];
  for (int j = tid; j < nb; j += 256) atomicAdd(&lcnt[eb[j] >> 17], 1);
  __syncthreads();
  if (tid == 0) {
    int run = 0;
#pragma unroll
    for (int j = 0; j < 64; ++j) { lbase[j] = run; run += lcnt[j]; }
  }
  __syncthreads();
  if (tid < 64) {
    int v = i * 64 + tid;
    if (v < N) {
      cnt[v] = lcnt[tid];
      rowptr[v] = i * BKCAP + lbase[tid];
    }
  }
  for (int j = tid; j < nb; j += 256) {
    unsigned u = eb[j];
    int ld = (int)(u >> 17);
    int r = atomicAdd(&lrank[ld], 1);
    esrc[(size_t)i * BKCAP + lbase[ld] + r] = (int)(u & 0x1FFFFu);
  }
}

// -------------------------------------------- layer-1 aggregation (weighted)
// h1 unscaled bf16:
//   ab1[v] = bf16(relu( dv_v*(sum_e h1[s]*dv_s + h1[v]*dv_v) + b1 ))
__global__ __launch_bounds__(256) void k_agg1(const unsigned short* __restrict__ h,
                                              const int* __restrict__ cnt,
                                              const int* __restrict__ rowptr,
                                              const int* __restrict__ esrc,
                                              const float* __restrict__ bias,
                                              unsigned short* __restrict__ out,
                                              int N) {
  const int v = blockIdx.x * 16 + (threadIdx.x >> 4);
  if (v >= N) return;
  const int lc = threadIdx.x & 15;
  const uint4* __restrict__ h4 = (const uint4*)h;

  const int deg = cnt[v];
  const float dv = rsqrtf((float)(deg + 1));
  float acc[8] = {0, 0, 0, 0, 0, 0, 0, 0};
  fma8(acc, h4[(size_t)v * 16 + lc], dv);  // self-loop (x dv again at end)
  const int* __restrict__ ep = &esrc[rowptr[v]];
  int e = 0;
  for (; e + 4 <= deg; e += 4) {
    int s0 = ep[e + 0], s1 = ep[e + 1], s2 = ep[e + 2], s3 = ep[e + 3];
    float w0 = rsqrtf((float)(cnt[s0] + 1));
    float w1 = rsqrtf((float)(cnt[s1] + 1));
    float w2 = rsqrtf((float)(cnt[s2] + 1));
    float w3 = rsqrtf((float)(cnt[s3] + 1));
    uint4 a0 = h4[(size_t)s0 * 16 + lc];
    uint4 a1 = h4[(size_t)s1 * 16 + lc];
    uint4 a2 = h4[(size_t)s2 * 16 + lc];
    uint4 a3 = h4[(size_t)s3 * 16 + lc];
    fma8(acc, a0, w0); fma8(acc, a1, w1); fma8(acc, a2, w2); fma8(acc, a3, w3);
  }
  for (; e < deg; ++e) {
    int s = ep[e];
    fma8(acc, h4[(size_t)s * 16 + lc], rsqrtf((float)(cnt[s] + 1)));
  }

  const float4 b0 = *(const float4*)&bias[lc * 8];
  const float4 b1 = *(const float4*)&bias[lc * 8 + 4];
  float r[8];
  r[0] = fmaxf(acc[0] * dv + b0.x, 0.0f);
  r[1] = fmaxf(acc[1] * dv + b0.y, 0.0f);
  r[2] = fmaxf(acc[2] * dv + b0.z, 0.0f);
  r[3] = fmaxf(acc[3] * dv + b0.w, 0.0f);
  r[4] = fmaxf(acc[4] * dv + b1.x, 0.0f);
  r[5] = fmaxf(acc[5] * dv + b1.y, 0.0f);
  r[6] = fmaxf(acc[6] * dv + b1.z, 0.0f);
  r[7] = fmaxf(acc[7] * dv + b1.w, 0.0f);
  uint4 pk = make_uint4(pack2(r[0], r[1]), pack2(r[2], r[3]),
                        pack2(r[4], r[5]), pack2(r[6], r[7]));
  ((uint4*)out)[(size_t)v * 16 + lc] = pk;
}

// -------------------------------------------------------- layer-2 GEMM
__global__ __launch_bounds__(256, 4) void k_gemm2(const unsigned short* __restrict__ X,
                                                  const float* __restrict__ W,
                                                  const int* __restrict__ cnt,
                                                  unsigned short* __restrict__ Y,
                                                  int N) {
  gemm_body<128, 64, true, true>(X, W, cnt, Y, N, blockIdx.x);
}

// ------------------------------------------- layer-2 aggregation (prescaled)
// out[v] = dv_v*(sum h2[s] + h2[v]) + b2   (fp32 out)
__global__ __launch_bounds__(256) void k_agg2(const unsigned short* __restrict__ h,
                                              const int* __restrict__ cnt,
                                              const int* __restrict__ rowptr,
                                              const int* __restrict__ esrc,
                                              const float* __restrict__ bias,
                                              float* __restrict__ out, int N) {
  constexpr int F = 64, LPN = 8, NPB = 32;
  const int v = blockIdx.x * NPB + threadIdx.x / LPN;
  if (v >= N) return;
  const int lc = threadIdx.x % LPN;
  const uint4* __restrict__ h4 = (const uint4*)h;

  float acc[8] = {0, 0, 0, 0, 0, 0, 0, 0};
  add8(acc, h4[(size_t)v * LPN + lc]);  // self-loop (dinv[v]-prescaled)
  const int deg = cnt[v];
  const float dv = rsqrtf((float)(deg + 1));
  const int* __restrict__ ep = &esrc[rowptr[v]];
  int e = 0;
  for (; e + 4 <= deg; e += 4) {
    int s0 = ep[e + 0], s1 = ep[e + 1], s2 = ep[e + 2], s3 = ep[e + 3];
    uint4 a0 = h4[(size_t)s0 * LPN + lc];
    uint4 a1 = h4[(size_t)s1 * LPN + lc];
    uint4 a2 = h4[(size_t)s2 * LPN + lc];
    uint4 a3 = h4[(size_t)s3 * LPN + lc];
    add8(acc, a0); add8(acc, a1); add8(acc, a2); add8(acc, a3);
  }
  for (; e < deg; ++e) add8(acc, h4[(size_t)ep[e] * LPN + lc]);

  const float4 b0 = *(const float4*)&bias[lc * 8];
  const float4 b1 = *(const float4*)&bias[lc * 8 + 4];
  float4 o0, o1;
  o0.x = acc[0] * dv + b0.x; o0.y = acc[1] * dv + b0.y;
  o0.z = acc[2] * dv + b0.z; o0.w = acc[3] * dv + b0.w;
  o1.x = acc[4] * dv + b1.x; o1.y = acc[5] * dv + b1.y;
  o1.z = acc[6] * dv + b1.z; o1.w = acc[7] * dv + b1.w;
  float4* op = (float4*)(out + (size_t)v * F + lc * 8);
  op[0] = o0; op[1] = o1;
}

// ---------------------------------------------------------------- launcher

extern "C" void kernel_launch(void* const* d_in, const int* in_sizes, int n_in,
                              void* d_out, int out_size, void* d_ws, size_t ws_size,
                              hipStream_t stream) {
  const float* x  = (const float*)d_in[0];
  const int*   ei = (const int*)d_in[1];
  const float* W1 = (const float*)d_in[2];
  const float* b1 = (const float*)d_in[3];
  const float* W2 = (const float*)d_in[4];
  const float* b2 = (const float*)d_in[5];
  const int H    = in_sizes[3];        // 128
  const int Fin  = in_sizes[2] / H;    // 128
  const int N    = in_sizes[0] / Fin;  // 50000 (<= 65536 for 17-bit packing)
  const int E    = in_sizes[1] / 2;    // 640000
  const int FO   = in_sizes[5];        // 64
  float* outp = (float*)d_out;

  const int NBK = CEILDIV(N, 64);      // 782 buckets
  const int FA  = CEILDIV(E, CHUNKA);  // 157 pass-A blocks
  const int GB  = CEILDIV(N, 128);     // 391 gemm1 blocks
  const int G1  = (GB * 2) / 5;        // gemm1 split: 40% in L1, 60% in L2

  char* p = (char*)d_ws;
  auto alloc = [&](size_t bytes) {
    void* q = (void*)p;
    p += (bytes + 255) & ~(size_t)255;
    return q;
  };
  int*      ctrl   = (int*)alloc((8 + MAXBK) * 4);
  int*      cnt    = (int*)alloc((size_t)N * 4);
  int*      rowptr = (int*)alloc((size_t)N * 4);
  unsigned* ebuf   = (unsigned*)alloc((size_t)NBK * BKCAP * 4);
  int*      esrc   = (int*)alloc((size_t)NBK * BKCAP * 4);
  unsigned short* hb1 = (unsigned short*)alloc((size_t)N * H * 2);   // bf16 h1 (unscaled)
  unsigned short* ab1 = (unsigned short*)alloc((size_t)N * H * 2);   // bf16 relu act
  unsigned short* hb2 = (unsigned short*)alloc((size_t)N * FO * 2);  // bf16 h2 (prescaled)

  k_init<<<1, 256, 0, stream>>>(ei, ctrl, E);
  // L1: bucket pass A (vectorized)  ||  gemm1 bids [0, G1)
  k_work1<<<FA + G1, 256, 0, stream>>>(x, W1, hb1, N, FA, ei, ctrl, ebuf, E, NBK);
  // L2: per-bucket local CSR (no global atomics, burst writes) || gemm1 rest
  k_work2<<<NBK + (GB - G1), 256, 0, stream>>>(x, W1, hb1, N, NBK, G1, ebuf,
                                               ctrl, cnt, rowptr, esrc);
  // ab1 = bf16(relu(dinv*(weighted agg h1) + b1))
  k_agg1<<<CEILDIV(N, 16), 256, 0, stream>>>(hb1, cnt, rowptr, esrc, b1, ab1, N);
  // hb2 = bf16((ab1 @ W2) * dinv)
  k_gemm2<<<CEILDIV(N, 128), 256, 0, stream>>>(ab1, W2, cnt, hb2, N);
  // out = dv*(agg h2 + self) + b2
  k_agg2<<<CEILDIV(N, 32), 256, 0, stream>>>(hb2, cnt, rowptr, esrc, b2, outp, N);
}